// Round 3
// baseline (183.538 us; speedup 1.0000x reference)
//
#include <hip/hip_runtime.h>

#define B_DIM 4096
#define L_DIM 2048
#define TPB   256
#define RPB   4        // rows per block = waves per block (independent, no barriers)
#define NG    8        // groups: 2048 floats / (64 lanes * 4 per float4)
#define TAU_INV 1.0526315789473684f

// One WAVE per row (zero __syncthreads in this kernel). Each thread owns 32
// elements as 8 strided float4 groups: element index = g*256 + lane*4 + j.
// Writes:
//   partials[row]         = sum_j log(t_j/tau) * q_j   (softmax-weighted)
//   partials[B_DIM + row] = sum_j sum_views (y*logp + (1-y)*log1mp)
__global__ __launch_bounds__(TPB) void milecut_row_kernel(
    const float* __restrict__ trunc,
    const float* __restrict__ view1,
    const float* __restrict__ view2,
    const float* __restrict__ view3,
    const float* __restrict__ labels,
    float* __restrict__ partials)
{
    const int lane = threadIdx.x & 63;
    const int wave = threadIdx.x >> 6;
    const int row  = blockIdx.x * RPB + wave;
    const size_t rowOff = (size_t)row * L_DIM;

    // ---- labels: 8 coalesced float4 loads, issued back-to-back ----
    const float4* yb = (const float4*)(labels + rowOff);
    float4 yv[NG];
    #pragma unroll
    for (int g = 0; g < NG; ++g) yv[g] = yb[g * 64 + lane];

    // prefetch group 0 of the 4 data arrays while the scan runs
    const float4* tb = (const float4*)(trunc + rowOff);
    const float4* b1 = (const float4*)(view1 + rowOff);
    const float4* b2 = (const float4*)(view2 + rowOff);
    const float4* b3 = (const float4*)(view3 + rowOff);
    float4 tc = tb[lane], c1 = b1[lane], c2 = b2[lane], c3 = b3[lane];

    // ---- per-group 4-sums + pack labels into a 32-bit mask ----
    float s4[NG];
    unsigned mask = 0;
    #pragma unroll
    for (int g = 0; g < NG; ++g) {
        float4 y = yv[g];
        s4[g] = (y.x + y.y) + (y.z + y.w);
        unsigned m = (y.x > 0.5f ? 1u : 0u) | (y.y > 0.5f ? 2u : 0u)
                   | (y.z > 0.5f ? 4u : 0u) | (y.w > 0.5f ? 8u : 0u);
        mask |= m << (g * 4);
    }

    // ---- 8 wave-level inclusive scans, interleaved (chains pipeline) ----
    float incl[NG];
    #pragma unroll
    for (int g = 0; g < NG; ++g) incl[g] = s4[g];
    #pragma unroll
    for (int off = 1; off < 64; off <<= 1) {
        #pragma unroll
        for (int g = 0; g < NG; ++g) {
            float n = __shfl_up(incl[g], off, 64);
            if (lane >= off) incl[g] += n;
        }
    }
    // exclusive group offsets + row total (exact small integers in fp32)
    float gpre[NG];
    float G = 0.f;
    #pragma unroll
    for (int g = 0; g < NG; ++g) {
        float gt = __shfl(incl[g], 63, 64);
        gpre[g] = G;
        G += gt;
    }
    const float total = G;

    // ---- fused main loop, 1-group-ahead software pipeline ----
    // r = (cum>0 ? 2*cum/(k+total) : 0) -> 2*cum/(k+total) works for cum==0 too.
    // e = exp(r/tau); softmax normalization deferred (divide by esum at end).
    // BCE with y in {0,1}: y*logp+(1-y)*log1mp == log(y ? p : 1-p), clamp -100.
    float esum = 0.f, wtr = 0.f, bce = 0.f;
    const float two_tauinv = 2.0f * TAU_INV;
    #pragma unroll
    for (int g = 0; g < NG; ++g) {
        float tv[4] = {tc.x, tc.y, tc.z, tc.w};
        float a1[4] = {c1.x, c1.y, c1.z, c1.w};
        float a2[4] = {c2.x, c2.y, c2.z, c2.w};
        float a3[4] = {c3.x, c3.y, c3.z, c3.w};
        if (g + 1 < NG) {
            tc = tb[(g + 1) * 64 + lane];
            c1 = b1[(g + 1) * 64 + lane];
            c2 = b2[(g + 1) * 64 + lane];
            c3 = b3[(g + 1) * 64 + lane];
        }
        float run = gpre[g] + (incl[g] - s4[g]);   // exclusive prefix at j=0
        const float base = (float)(g * 256 + lane * 4 + 1) + total;
        #pragma unroll
        for (int j = 0; j < 4; ++j) {
            bool pos = (mask >> (g * 4 + j)) & 1u;
            run += pos ? 1.0f : 0.0f;              // inclusive cumsum
            float denom = base + (float)j;
            float e = __expf((two_tauinv * run) * __builtin_amdgcn_rcpf(denom));
            esum += e;
            wtr += __logf(tv[j] * TAU_INV) * e;
            float q1 = pos ? a1[j] : 1.0f - a1[j];
            float q2 = pos ? a2[j] : 1.0f - a2[j];
            float q3 = pos ? a3[j] : 1.0f - a3[j];
            bce += fmaxf(__logf(q1), -100.0f);
            bce += fmaxf(__logf(q2), -100.0f);
            bce += fmaxf(__logf(q3), -100.0f);
        }
    }

    // ---- wave butterfly reduce (esum, wtr, bce) ----
    #pragma unroll
    for (int off = 32; off > 0; off >>= 1) {
        esum += __shfl_down(esum, off, 64);
        wtr  += __shfl_down(wtr,  off, 64);
        bce  += __shfl_down(bce,  off, 64);
    }
    if (lane == 0) {
        partials[row]         = wtr / esum;  // row's sum_j log(t/tau)*q_j
        partials[B_DIM + row] = bce;         // row's raw combined bce sum
    }
}

__global__ __launch_bounds__(TPB) void milecut_final_kernel(
    const float* __restrict__ partials, float* __restrict__ out)
{
    const int t = threadIdx.x;
    const float4* p4 = (const float4*)partials;   // 2048 float4 total
    float st = 0.f, sb = 0.f;
    #pragma unroll
    for (int i = 0; i < 4; ++i) {                 // trunc part: f4 idx 0..1023
        float4 a = p4[t + 256 * i];
        st += (a.x + a.y) + (a.z + a.w);
    }
    #pragma unroll
    for (int i = 4; i < 8; ++i) {                 // bce part: f4 idx 1024..2047
        float4 a = p4[t + 256 * i];
        sb += (a.x + a.y) + (a.z + a.w);
    }
    #pragma unroll
    for (int off = 32; off > 0; off >>= 1) {
        st += __shfl_down(st, off, 64);
        sb += __shfl_down(sb, off, 64);
    }
    __shared__ float s1[RPB], s2[RPB];
    const int lane = t & 63, wave = t >> 6;
    if (lane == 0) { s1[wave] = st; s2[wave] = sb; }
    __syncthreads();
    if (t == 0) {
        double St = 0.0, Sb = 0.0;
        #pragma unroll
        for (int w = 0; w < RPB; ++w) { St += (double)s1[w]; Sb += (double)s2[w]; }
        double trunc_loss = -St / (double)B_DIM;                        // -sum(log*q)/B
        double vsum = -Sb / ((double)B_DIM * (double)L_DIM * (double)B_DIM);
        out[0] = (float)(0.5 * trunc_loss + 0.5 * vsum);
    }
}

extern "C" void kernel_launch(void* const* d_in, const int* in_sizes, int n_in,
                              void* d_out, int out_size, void* d_ws, size_t ws_size,
                              hipStream_t stream) {
    const float* trunc  = (const float*)d_in[0];
    const float* v1     = (const float*)d_in[1];
    const float* v2     = (const float*)d_in[2];
    const float* v3     = (const float*)d_in[3];
    const float* labels = (const float*)d_in[4];

    float* partials = (float*)d_ws;  // 2*B_DIM*4 = 32 KB

    milecut_row_kernel<<<B_DIM / RPB, TPB, 0, stream>>>(trunc, v1, v2, v3, labels, partials);
    milecut_final_kernel<<<1, TPB, 0, stream>>>(partials, (float*)d_out);
}

// Round 4
// 182.982 us; speedup vs baseline: 1.0030x; 1.0030x over previous
//
#include <hip/hip_runtime.h>

#define B_DIM 4096
#define L_DIM 2048
#define TPB   256
#define RPB   4        // rows per block = waves per block (independent, no barriers)
#define NG    8        // groups: 2048 floats / (64 lanes * 4 per float4)
#define TAU_INV 1.0526315789473684f

// One WAVE per row, zero barriers. Each thread owns 32 elements as 8 strided
// float4 groups: element index = g*256 + lane*4 + j.
// KEY: all 40 float4 loads (5 arrays x 8 groups) are issued UP FRONT so each
// wave keeps ~40KB in flight (Little's law: this is what saturates HBM, not
// occupancy). Scan + compute run under the load shadow with partial vmcnt
// waits inserted by the compiler.
// Writes:
//   partials[row]         = sum_j log(t_j/tau) * q_j   (softmax-weighted)
//   partials[B_DIM + row] = sum_j sum_views (y*logp + (1-y)*log1mp)
__global__ __launch_bounds__(TPB, 2) void milecut_row_kernel(
    const float* __restrict__ trunc,
    const float* __restrict__ view1,
    const float* __restrict__ view2,
    const float* __restrict__ view3,
    const float* __restrict__ labels,
    float* __restrict__ partials)
{
    const int lane = threadIdx.x & 63;
    const int wave = threadIdx.x >> 6;
    const int row  = blockIdx.x * RPB + wave;
    const size_t rowOff = (size_t)row * L_DIM;

    const float4* yb = (const float4*)(labels + rowOff);
    const float4* tb = (const float4*)(trunc  + rowOff);
    const float4* b1 = (const float4*)(view1  + rowOff);
    const float4* b2 = (const float4*)(view2  + rowOff);
    const float4* b3 = (const float4*)(view3  + rowOff);

    // ---- issue ALL loads back-to-back: labels first, then data in
    //      consumption order (group-major) ----
    float4 yv[NG];
    #pragma unroll
    for (int g = 0; g < NG; ++g) yv[g] = yb[g * 64 + lane];

    float4 td[NG], d1[NG], d2[NG], d3[NG];
    #pragma unroll
    for (int g = 0; g < NG; ++g) {
        td[g] = tb[g * 64 + lane];
        d1[g] = b1[g * 64 + lane];
        d2[g] = b2[g * 64 + lane];
        d3[g] = b3[g * 64 + lane];
    }

    // ---- per-group 4-sums + pack labels into a 32-bit mask (frees yv) ----
    float s4[NG];
    unsigned mask = 0;
    #pragma unroll
    for (int g = 0; g < NG; ++g) {
        float4 y = yv[g];
        s4[g] = (y.x + y.y) + (y.z + y.w);
        unsigned m = (y.x > 0.5f ? 1u : 0u) | (y.y > 0.5f ? 2u : 0u)
                   | (y.z > 0.5f ? 4u : 0u) | (y.w > 0.5f ? 8u : 0u);
        mask |= m << (g * 4);
    }

    // ---- 8 interleaved wave-level inclusive scans (runs under load shadow) ----
    float incl[NG];
    #pragma unroll
    for (int g = 0; g < NG; ++g) incl[g] = s4[g];
    #pragma unroll
    for (int off = 1; off < 64; off <<= 1) {
        #pragma unroll
        for (int g = 0; g < NG; ++g) {
            float n = __shfl_up(incl[g], off, 64);
            if (lane >= off) incl[g] += n;
        }
    }
    // exclusive group offsets + row total (exact small integers in fp32)
    float gpre[NG];
    float G = 0.f;
    #pragma unroll
    for (int g = 0; g < NG; ++g) {
        float gt = __shfl(incl[g], 63, 64);
        gpre[g] = G;
        G += gt;
    }
    const float total = G;

    // ---- fused main loop; data already in registers (vmcnt waits only) ----
    // r = 2*cum/(k+total) (valid for cum==0 too); e = exp(r/tau); softmax
    // normalization deferred. BCE with y in {0,1}: log(y ? p : 1-p), clamp -100.
    float esum = 0.f, wtr = 0.f, bce = 0.f;
    const float two_tauinv = 2.0f * TAU_INV;
    #pragma unroll
    for (int g = 0; g < NG; ++g) {
        float tv[4] = {td[g].x, td[g].y, td[g].z, td[g].w};
        float a1[4] = {d1[g].x, d1[g].y, d1[g].z, d1[g].w};
        float a2[4] = {d2[g].x, d2[g].y, d2[g].z, d2[g].w};
        float a3[4] = {d3[g].x, d3[g].y, d3[g].z, d3[g].w};
        float run = gpre[g] + (incl[g] - s4[g]);   // exclusive prefix at j=0
        const float base = (float)(g * 256 + lane * 4 + 1) + total;
        #pragma unroll
        for (int j = 0; j < 4; ++j) {
            bool pos = (mask >> (g * 4 + j)) & 1u;
            run += pos ? 1.0f : 0.0f;              // inclusive cumsum
            float denom = base + (float)j;
            float e = __expf((two_tauinv * run) * __builtin_amdgcn_rcpf(denom));
            esum += e;
            wtr += __logf(tv[j] * TAU_INV) * e;
            float q1 = pos ? a1[j] : 1.0f - a1[j];
            float q2 = pos ? a2[j] : 1.0f - a2[j];
            float q3 = pos ? a3[j] : 1.0f - a3[j];
            bce += fmaxf(__logf(q1), -100.0f);
            bce += fmaxf(__logf(q2), -100.0f);
            bce += fmaxf(__logf(q3), -100.0f);
        }
    }

    // ---- wave butterfly reduce (esum, wtr, bce) ----
    #pragma unroll
    for (int off = 32; off > 0; off >>= 1) {
        esum += __shfl_down(esum, off, 64);
        wtr  += __shfl_down(wtr,  off, 64);
        bce  += __shfl_down(bce,  off, 64);
    }
    if (lane == 0) {
        partials[row]         = wtr / esum;  // row's sum_j log(t/tau)*q_j
        partials[B_DIM + row] = bce;         // row's raw combined bce sum
    }
}

__global__ __launch_bounds__(TPB) void milecut_final_kernel(
    const float* __restrict__ partials, float* __restrict__ out)
{
    const int t = threadIdx.x;
    const float4* p4 = (const float4*)partials;   // 2048 float4 total
    float st = 0.f, sb = 0.f;
    #pragma unroll
    for (int i = 0; i < 4; ++i) {                 // trunc part: f4 idx 0..1023
        float4 a = p4[t + 256 * i];
        st += (a.x + a.y) + (a.z + a.w);
    }
    #pragma unroll
    for (int i = 4; i < 8; ++i) {                 // bce part: f4 idx 1024..2047
        float4 a = p4[t + 256 * i];
        sb += (a.x + a.y) + (a.z + a.w);
    }
    #pragma unroll
    for (int off = 32; off > 0; off >>= 1) {
        st += __shfl_down(st, off, 64);
        sb += __shfl_down(sb, off, 64);
    }
    __shared__ float s1[RPB], s2[RPB];
    const int lane = t & 63, wave = t >> 6;
    if (lane == 0) { s1[wave] = st; s2[wave] = sb; }
    __syncthreads();
    if (t == 0) {
        double St = 0.0, Sb = 0.0;
        #pragma unroll
        for (int w = 0; w < RPB; ++w) { St += (double)s1[w]; Sb += (double)s2[w]; }
        double trunc_loss = -St / (double)B_DIM;                        // -sum(log*q)/B
        double vsum = -Sb / ((double)B_DIM * (double)L_DIM * (double)B_DIM);
        out[0] = (float)(0.5 * trunc_loss + 0.5 * vsum);
    }
}

extern "C" void kernel_launch(void* const* d_in, const int* in_sizes, int n_in,
                              void* d_out, int out_size, void* d_ws, size_t ws_size,
                              hipStream_t stream) {
    const float* trunc  = (const float*)d_in[0];
    const float* v1     = (const float*)d_in[1];
    const float* v2     = (const float*)d_in[2];
    const float* v3     = (const float*)d_in[3];
    const float* labels = (const float*)d_in[4];

    float* partials = (float*)d_ws;  // 2*B_DIM*4 = 32 KB

    milecut_row_kernel<<<B_DIM / RPB, TPB, 0, stream>>>(trunc, v1, v2, v3, labels, partials);
    milecut_final_kernel<<<1, TPB, 0, stream>>>(partials, (float*)d_out);
}

// Round 5
// 181.244 us; speedup vs baseline: 1.0127x; 1.0096x over previous
//
#include <hip/hip_runtime.h>

#define B_DIM 4096
#define L_DIM 2048
#define TPB   256
#define RPB   4                  // rows processed sequentially per block
#define NW    4                  // waves per block
#define NBLK  (B_DIM / RPB)      // 1024 blocks
#define TAU_INV 1.0526315789473684f

// Block per RPB rows, software-pipelined: row r+1's 10 float4 loads are issued
// before row r's compute so ~10KB/wave stays in flight across the whole row
// body. Labels handled as bitmasks: packed (lo16,hi16) integer wave scan +
// __popc for per-element cumsum. 2 barriers per row (cross-wave scan only).
// Writes per block:
//   partials[blk]        = sum over its 4 rows of (sum_j log(t/tau)*q_j)
//   partials[NBLK + blk] = raw combined bce sum over its 4 rows
__global__ __launch_bounds__(TPB) void milecut_row_kernel(
    const float* __restrict__ trunc,
    const float* __restrict__ view1,
    const float* __restrict__ view2,
    const float* __restrict__ view3,
    const float* __restrict__ labels,
    float* __restrict__ partials)
{
    const int t    = threadIdx.x;
    const int lane = t & 63;
    const int wv   = t >> 6;
    const int row0 = blockIdx.x * RPB;

    __shared__ unsigned swtot[NW];       // packed wave scan totals (reused per row)
    __shared__ float    srow[RPB][NW][2];// (esum, wtr) per row per wave
    __shared__ float    sbce[NW];

    // ---- prefetch row 0: 10 independent fully-coalesced 16B loads ----
    size_t off = (size_t)row0 * L_DIM;
    float4 nya = ((const float4*)(labels + off))[t];
    float4 nyb = ((const float4*)(labels + off))[t + 256];
    float4 nta = ((const float4*)(trunc  + off))[t];
    float4 ntb = ((const float4*)(trunc  + off))[t + 256];
    float4 n1a = ((const float4*)(view1  + off))[t];
    float4 n1b = ((const float4*)(view1  + off))[t + 256];
    float4 n2a = ((const float4*)(view2  + off))[t];
    float4 n2b = ((const float4*)(view2  + off))[t + 256];
    float4 n3a = ((const float4*)(view3  + off))[t];
    float4 n3b = ((const float4*)(view3  + off))[t + 256];

    float bce = 0.f;   // per-thread, across all RPB rows

    #pragma unroll
    for (int rr = 0; rr < RPB; ++rr) {
        // move current row into working regs
        float4 ya = nya, yb = nyb, ta = nta, tb = ntb;
        float4 u1a = n1a, u1b = n1b, u2a = n2a, u2b = n2b, u3a = n3a, u3b = n3b;
        // issue next row's loads NOW (consumed only next iteration)
        if (rr + 1 < RPB) {
            size_t o2 = (size_t)(row0 + rr + 1) * L_DIM;
            nya = ((const float4*)(labels + o2))[t];
            nyb = ((const float4*)(labels + o2))[t + 256];
            nta = ((const float4*)(trunc  + o2))[t];
            ntb = ((const float4*)(trunc  + o2))[t + 256];
            n1a = ((const float4*)(view1  + o2))[t];
            n1b = ((const float4*)(view1  + o2))[t + 256];
            n2a = ((const float4*)(view2  + o2))[t];
            n2b = ((const float4*)(view2  + o2))[t + 256];
            n3a = ((const float4*)(view3  + o2))[t];
            n3b = ((const float4*)(view3  + o2))[t + 256];
        }

        // ---- label bitmasks; thread owns elements [4t..4t+3] and [1024+4t..] ----
        unsigned m1 = (ya.x > 0.5f ? 1u : 0u) | (ya.y > 0.5f ? 2u : 0u)
                    | (ya.z > 0.5f ? 4u : 0u) | (ya.w > 0.5f ? 8u : 0u);
        unsigned m2 = (yb.x > 0.5f ? 1u : 0u) | (yb.y > 0.5f ? 2u : 0u)
                    | (yb.z > 0.5f ? 4u : 0u) | (yb.w > 0.5f ? 8u : 0u);
        // packed per-thread sums: lo16 = group1 count, hi16 = group2 count
        unsigned pv = (unsigned)__popc(m1) | ((unsigned)__popc(m2) << 16);

        // ---- single packed inclusive wave scan (6 shfls) ----
        unsigned incl = pv;
        #pragma unroll
        for (int o = 1; o < 64; o <<= 1) {
            unsigned n = (unsigned)__shfl_up((int)incl, o, 64);
            if (lane >= o) incl += n;
        }
        if (lane == 63) swtot[wv] = incl;
        __syncthreads();
        unsigned pref = 0, tot = 0;
        #pragma unroll
        for (int w = 0; w < NW; ++w) {
            unsigned x = swtot[w];
            if (w < wv) pref += x;
            tot += x;
        }
        __syncthreads();   // protects swtot reuse next row

        unsigned eo    = incl - pv;                       // exclusive, packed (no borrow)
        unsigned excl1 = (pref & 0xffffu) + (eo & 0xffffu);
        unsigned tot1  = tot & 0xffffu;
        unsigned excl2 = tot1 + (pref >> 16) + (eo >> 16);
        float ftotal   = (float)(tot1 + (tot >> 16));     // row label total

        // ---- fused elementwise: r=2*cum/(k+total), e=exp(r/tau),
        //      wtr += log(t/tau)*e; bce (y in {0,1}): log(y?p:1-p) clamp -100 ----
        float esum = 0.f, wtr = 0.f;
        float tva[4] = {ta.x, ta.y, ta.z, ta.w};
        float tvb[4] = {tb.x, tb.y, tb.z, tb.w};
        float w1a[4] = {u1a.x, u1a.y, u1a.z, u1a.w};
        float w1b[4] = {u1b.x, u1b.y, u1b.z, u1b.w};
        float w2a[4] = {u2a.x, u2a.y, u2a.z, u2a.w};
        float w2b[4] = {u2b.x, u2b.y, u2b.z, u2b.w};
        float w3a[4] = {u3a.x, u3a.y, u3a.z, u3a.w};
        float w3b[4] = {u3b.x, u3b.y, u3b.z, u3b.w};
        const float two_tauinv = 2.0f * TAU_INV;
        #pragma unroll
        for (int j = 0; j < 4; ++j) {
            // group 1: element 4t+j (k = 4t+j+1)
            unsigned c1 = excl1 + (unsigned)__popc(m1 & ((2u << j) - 1u));
            float d1 = (float)(4 * t + j + 1) + ftotal;
            float e1 = __expf(two_tauinv * (float)c1 * __builtin_amdgcn_rcpf(d1));
            esum += e1;
            wtr  += __logf(tva[j] * TAU_INV) * e1;
            bool p1 = (m1 >> j) & 1u;
            bce += fmaxf(__logf(p1 ? w1a[j] : 1.f - w1a[j]), -100.f);
            bce += fmaxf(__logf(p1 ? w2a[j] : 1.f - w2a[j]), -100.f);
            bce += fmaxf(__logf(p1 ? w3a[j] : 1.f - w3a[j]), -100.f);
            // group 2: element 1024+4t+j
            unsigned c2 = excl2 + (unsigned)__popc(m2 & ((2u << j) - 1u));
            float d2 = (float)(1024 + 4 * t + j + 1) + ftotal;
            float e2 = __expf(two_tauinv * (float)c2 * __builtin_amdgcn_rcpf(d2));
            esum += e2;
            wtr  += __logf(tvb[j] * TAU_INV) * e2;
            bool p2 = (m2 >> j) & 1u;
            bce += fmaxf(__logf(p2 ? w1b[j] : 1.f - w1b[j]), -100.f);
            bce += fmaxf(__logf(p2 ? w2b[j] : 1.f - w2b[j]), -100.f);
            bce += fmaxf(__logf(p2 ? w3b[j] : 1.f - w3b[j]), -100.f);
        }

        // ---- wave-local reduce (no barrier); stash in per-(row,wave) slot ----
        #pragma unroll
        for (int o = 32; o > 0; o >>= 1) {
            esum += __shfl_down(esum, o, 64);
            wtr  += __shfl_down(wtr,  o, 64);
        }
        if (lane == 0) { srow[rr][wv][0] = esum; srow[rr][wv][1] = wtr; }
    }

    // ---- epilogue: bce wave reduce + single combine ----
    #pragma unroll
    for (int o = 32; o > 0; o >>= 1) bce += __shfl_down(bce, o, 64);
    if (lane == 0) sbce[wv] = bce;
    __syncthreads();
    if (t == 0) {
        float btot = sbce[0] + sbce[1] + sbce[2] + sbce[3];
        float atr = 0.f;
        #pragma unroll
        for (int rr = 0; rr < RPB; ++rr) {
            float es = srow[rr][0][0] + srow[rr][1][0] + srow[rr][2][0] + srow[rr][3][0];
            float wt = srow[rr][0][1] + srow[rr][1][1] + srow[rr][2][1] + srow[rr][3][1];
            atr += wt / es;             // this row's sum_j log(t/tau)*q_j
        }
        partials[blockIdx.x]        = atr;
        partials[NBLK + blockIdx.x] = btot;
    }
}

__global__ __launch_bounds__(TPB) void milecut_final_kernel(
    const float* __restrict__ partials, float* __restrict__ out)
{
    const int t = threadIdx.x;
    const float4* p4 = (const float4*)partials;   // 512 float4 total
    float4 a = p4[t];          // trunc region: f4 0..255
    float4 b = p4[256 + t];    // bce region:   f4 256..511
    float st = (a.x + a.y) + (a.z + a.w);
    float sb = (b.x + b.y) + (b.z + b.w);
    #pragma unroll
    for (int o = 32; o > 0; o >>= 1) {
        st += __shfl_down(st, o, 64);
        sb += __shfl_down(sb, o, 64);
    }
    __shared__ float s1[NW], s2[NW];
    const int lane = t & 63, wv = t >> 6;
    if (lane == 0) { s1[wv] = st; s2[wv] = sb; }
    __syncthreads();
    if (t == 0) {
        double St = 0.0, Sb = 0.0;
        #pragma unroll
        for (int w = 0; w < NW; ++w) { St += (double)s1[w]; Sb += (double)s2[w]; }
        double trunc_loss = -St / (double)B_DIM;                         // -sum(log*q)/B
        double vsum = -Sb / ((double)B_DIM * (double)L_DIM * (double)B_DIM);
        out[0] = (float)(0.5 * trunc_loss + 0.5 * vsum);
    }
}

extern "C" void kernel_launch(void* const* d_in, const int* in_sizes, int n_in,
                              void* d_out, int out_size, void* d_ws, size_t ws_size,
                              hipStream_t stream) {
    const float* trunc  = (const float*)d_in[0];
    const float* v1     = (const float*)d_in[1];
    const float* v2     = (const float*)d_in[2];
    const float* v3     = (const float*)d_in[3];
    const float* labels = (const float*)d_in[4];

    float* partials = (float*)d_ws;  // 2*NBLK*4 = 8 KB used

    milecut_row_kernel<<<NBLK, TPB, 0, stream>>>(trunc, v1, v2, v3, labels, partials);
    milecut_final_kernel<<<1, TPB, 0, stream>>>(partials, (float*)d_out);
}

// Round 6
// 167.700 us; speedup vs baseline: 1.0944x; 1.0808x over previous
//
#include <hip/hip_runtime.h>

#define B_DIM 4096
#define L_DIM 2048
#define TPB   256
#define RPB   4                  // rows processed sequentially per block
#define NW    4                  // waves per block
#define NBLK  (B_DIM / RPB)      // 1024 blocks
#define TAU_INV 1.0526315789473684f

typedef float v4f __attribute__((ext_vector_type(4)));

// Nontemporal float4 load: bypasses cache allocation (emits 'nt' flag).
// A/B vs R5: ONLY the load instructions differ.
__device__ __forceinline__ v4f ntload(const float* p) {
    return __builtin_nontemporal_load((const v4f*)p);
}

// Block per RPB rows, software-pipelined (identical structure to R5), but all
// input reads are NONTEMPORAL to avoid L2/L3 allocation + dirty-line
// replacement traffic from the harness's input-restore.
// Writes per block:
//   partials[blk]        = sum over its 4 rows of (sum_j log(t/tau)*q_j)
//   partials[NBLK + blk] = raw combined bce sum over its 4 rows
__global__ __launch_bounds__(TPB) void milecut_row_kernel(
    const float* __restrict__ trunc,
    const float* __restrict__ view1,
    const float* __restrict__ view2,
    const float* __restrict__ view3,
    const float* __restrict__ labels,
    float* __restrict__ partials)
{
    const int t    = threadIdx.x;
    const int lane = t & 63;
    const int wv   = t >> 6;
    const int row0 = blockIdx.x * RPB;

    __shared__ unsigned swtot[NW];        // packed wave scan totals (reused per row)
    __shared__ float    srow[RPB][NW][2]; // (esum, wtr) per row per wave
    __shared__ float    sbce[NW];

    // ---- prefetch row 0: 10 independent fully-coalesced nontemporal 16B loads ----
    size_t off = (size_t)row0 * L_DIM;
    v4f nya = ntload(labels + off + 4 * t);
    v4f nyb = ntload(labels + off + 4 * (t + 256));
    v4f nta = ntload(trunc  + off + 4 * t);
    v4f ntb = ntload(trunc  + off + 4 * (t + 256));
    v4f n1a = ntload(view1  + off + 4 * t);
    v4f n1b = ntload(view1  + off + 4 * (t + 256));
    v4f n2a = ntload(view2  + off + 4 * t);
    v4f n2b = ntload(view2  + off + 4 * (t + 256));
    v4f n3a = ntload(view3  + off + 4 * t);
    v4f n3b = ntload(view3  + off + 4 * (t + 256));

    float bce = 0.f;   // per-thread, across all RPB rows

    #pragma unroll
    for (int rr = 0; rr < RPB; ++rr) {
        // move current row into working regs
        v4f ya = nya, yb = nyb, ta = nta, tb = ntb;
        v4f u1a = n1a, u1b = n1b, u2a = n2a, u2b = n2b, u3a = n3a, u3b = n3b;
        // issue next row's loads NOW (consumed only next iteration)
        if (rr + 1 < RPB) {
            size_t o2 = (size_t)(row0 + rr + 1) * L_DIM;
            nya = ntload(labels + o2 + 4 * t);
            nyb = ntload(labels + o2 + 4 * (t + 256));
            nta = ntload(trunc  + o2 + 4 * t);
            ntb = ntload(trunc  + o2 + 4 * (t + 256));
            n1a = ntload(view1  + o2 + 4 * t);
            n1b = ntload(view1  + o2 + 4 * (t + 256));
            n2a = ntload(view2  + o2 + 4 * t);
            n2b = ntload(view2  + o2 + 4 * (t + 256));
            n3a = ntload(view3  + o2 + 4 * t);
            n3b = ntload(view3  + o2 + 4 * (t + 256));
        }

        // ---- label bitmasks; thread owns elements [4t..4t+3] and [1024+4t..] ----
        unsigned m1 = (ya.x > 0.5f ? 1u : 0u) | (ya.y > 0.5f ? 2u : 0u)
                    | (ya.z > 0.5f ? 4u : 0u) | (ya.w > 0.5f ? 8u : 0u);
        unsigned m2 = (yb.x > 0.5f ? 1u : 0u) | (yb.y > 0.5f ? 2u : 0u)
                    | (yb.z > 0.5f ? 4u : 0u) | (yb.w > 0.5f ? 8u : 0u);
        // packed per-thread sums: lo16 = group1 count, hi16 = group2 count
        unsigned pv = (unsigned)__popc(m1) | ((unsigned)__popc(m2) << 16);

        // ---- single packed inclusive wave scan (6 shfls) ----
        unsigned incl = pv;
        #pragma unroll
        for (int o = 1; o < 64; o <<= 1) {
            unsigned n = (unsigned)__shfl_up((int)incl, o, 64);
            if (lane >= o) incl += n;
        }
        if (lane == 63) swtot[wv] = incl;
        __syncthreads();
        unsigned pref = 0, tot = 0;
        #pragma unroll
        for (int w = 0; w < NW; ++w) {
            unsigned x = swtot[w];
            if (w < wv) pref += x;
            tot += x;
        }
        __syncthreads();   // protects swtot reuse next row

        unsigned eo    = incl - pv;                       // exclusive, packed (no borrow)
        unsigned excl1 = (pref & 0xffffu) + (eo & 0xffffu);
        unsigned tot1  = tot & 0xffffu;
        unsigned excl2 = tot1 + (pref >> 16) + (eo >> 16);
        float ftotal   = (float)(tot1 + (tot >> 16));     // row label total

        // ---- fused elementwise: r=2*cum/(k+total), e=exp(r/tau),
        //      wtr += log(t/tau)*e; bce (y in {0,1}): log(y?p:1-p) clamp -100 ----
        float esum = 0.f, wtr = 0.f;
        float tva[4] = {ta.x, ta.y, ta.z, ta.w};
        float tvb[4] = {tb.x, tb.y, tb.z, tb.w};
        float w1a[4] = {u1a.x, u1a.y, u1a.z, u1a.w};
        float w1b[4] = {u1b.x, u1b.y, u1b.z, u1b.w};
        float w2a[4] = {u2a.x, u2a.y, u2a.z, u2a.w};
        float w2b[4] = {u2b.x, u2b.y, u2b.z, u2b.w};
        float w3a[4] = {u3a.x, u3a.y, u3a.z, u3a.w};
        float w3b[4] = {u3b.x, u3b.y, u3b.z, u3b.w};
        const float two_tauinv = 2.0f * TAU_INV;
        #pragma unroll
        for (int j = 0; j < 4; ++j) {
            // group 1: element 4t+j (k = 4t+j+1)
            unsigned c1 = excl1 + (unsigned)__popc(m1 & ((2u << j) - 1u));
            float d1 = (float)(4 * t + j + 1) + ftotal;
            float e1 = __expf(two_tauinv * (float)c1 * __builtin_amdgcn_rcpf(d1));
            esum += e1;
            wtr  += __logf(tva[j] * TAU_INV) * e1;
            bool p1 = (m1 >> j) & 1u;
            bce += fmaxf(__logf(p1 ? w1a[j] : 1.f - w1a[j]), -100.f);
            bce += fmaxf(__logf(p1 ? w2a[j] : 1.f - w2a[j]), -100.f);
            bce += fmaxf(__logf(p1 ? w3a[j] : 1.f - w3a[j]), -100.f);
            // group 2: element 1024+4t+j
            unsigned c2 = excl2 + (unsigned)__popc(m2 & ((2u << j) - 1u));
            float d2 = (float)(1024 + 4 * t + j + 1) + ftotal;
            float e2 = __expf(two_tauinv * (float)c2 * __builtin_amdgcn_rcpf(d2));
            esum += e2;
            wtr  += __logf(tvb[j] * TAU_INV) * e2;
            bool p2 = (m2 >> j) & 1u;
            bce += fmaxf(__logf(p2 ? w1b[j] : 1.f - w1b[j]), -100.f);
            bce += fmaxf(__logf(p2 ? w2b[j] : 1.f - w2b[j]), -100.f);
            bce += fmaxf(__logf(p2 ? w3b[j] : 1.f - w3b[j]), -100.f);
        }

        // ---- wave-local reduce (no barrier); stash in per-(row,wave) slot ----
        #pragma unroll
        for (int o = 32; o > 0; o >>= 1) {
            esum += __shfl_down(esum, o, 64);
            wtr  += __shfl_down(wtr,  o, 64);
        }
        if (lane == 0) { srow[rr][wv][0] = esum; srow[rr][wv][1] = wtr; }
    }

    // ---- epilogue: bce wave reduce + single combine ----
    #pragma unroll
    for (int o = 32; o > 0; o >>= 1) bce += __shfl_down(bce, o, 64);
    if (lane == 0) sbce[wv] = bce;
    __syncthreads();
    if (t == 0) {
        float btot = sbce[0] + sbce[1] + sbce[2] + sbce[3];
        float atr = 0.f;
        #pragma unroll
        for (int rr = 0; rr < RPB; ++rr) {
            float es = srow[rr][0][0] + srow[rr][1][0] + srow[rr][2][0] + srow[rr][3][0];
            float wt = srow[rr][0][1] + srow[rr][1][1] + srow[rr][2][1] + srow[rr][3][1];
            atr += wt / es;             // this row's sum_j log(t/tau)*q_j
        }
        partials[blockIdx.x]        = atr;
        partials[NBLK + blockIdx.x] = btot;
    }
}

__global__ __launch_bounds__(TPB) void milecut_final_kernel(
    const float* __restrict__ partials, float* __restrict__ out)
{
    const int t = threadIdx.x;
    const float4* p4 = (const float4*)partials;   // 512 float4 total
    float4 a = p4[t];          // trunc region: f4 0..255
    float4 b = p4[256 + t];    // bce region:   f4 256..511
    float st = (a.x + a.y) + (a.z + a.w);
    float sb = (b.x + b.y) + (b.z + b.w);
    #pragma unroll
    for (int o = 32; o > 0; o >>= 1) {
        st += __shfl_down(st, o, 64);
        sb += __shfl_down(sb, o, 64);
    }
    __shared__ float s1[NW], s2[NW];
    const int lane = t & 63, wv = t >> 6;
    if (lane == 0) { s1[wv] = st; s2[wv] = sb; }
    __syncthreads();
    if (t == 0) {
        double St = 0.0, Sb = 0.0;
        #pragma unroll
        for (int w = 0; w < NW; ++w) { St += (double)s1[w]; Sb += (double)s2[w]; }
        double trunc_loss = -St / (double)B_DIM;                         // -sum(log*q)/B
        double vsum = -Sb / ((double)B_DIM * (double)L_DIM * (double)B_DIM);
        out[0] = (float)(0.5 * trunc_loss + 0.5 * vsum);
    }
}

extern "C" void kernel_launch(void* const* d_in, const int* in_sizes, int n_in,
                              void* d_out, int out_size, void* d_ws, size_t ws_size,
                              hipStream_t stream) {
    const float* trunc  = (const float*)d_in[0];
    const float* v1     = (const float*)d_in[1];
    const float* v2     = (const float*)d_in[2];
    const float* v3     = (const float*)d_in[3];
    const float* labels = (const float*)d_in[4];

    float* partials = (float*)d_ws;  // 2*NBLK*4 = 8 KB used

    milecut_row_kernel<<<NBLK, TPB, 0, stream>>>(trunc, v1, v2, v3, labels, partials);
    milecut_final_kernel<<<1, TPB, 0, stream>>>(partials, (float*)d_out);
}

// Round 7
// 161.946 us; speedup vs baseline: 1.1333x; 1.0355x over previous
//
#include <hip/hip_runtime.h>

#define B_DIM 4096
#define L_DIM 2048
#define TPB   256
#define RPB   4                  // rows processed sequentially per block
#define NW    4                  // waves per block
#define NBLK  (B_DIM / RPB)      // 1024 blocks
#define TAU_INV 1.0526315789473684f
#define LOG_TAU_INV 0.05129329438755058f   // ln(1/0.95)

typedef float v4f __attribute__((ext_vector_type(4)));

// Nontemporal float4 load ('nt' flag): bypasses cache allocation — avoids the
// L3 dirty-line service path left by the harness's input restore (R6: −13.5us).
__device__ __forceinline__ v4f ntload(const float* p) {
    return __builtin_nontemporal_load((const v4f*)p);
}

// Block per RPB rows, software-pipelined next-row prefetch (R5/R6 structure).
// R7: transcendental diet — 6 BCE logs/element-pair fused into ONE product-log
// (clamp at -100 provably inactive: p in (1e-4,1-1e-4) => log >= -9.22; product
// of 6 factors >= 1e-24 >> FLT_MIN), and log(1/tau) hoisted out of the trunc
// weighted sum.
// Writes per block:
//   partials[blk]        = sum over its 4 rows of (sum_j log(t/tau)*q_j)
//   partials[NBLK + blk] = raw combined bce sum over its 4 rows
__global__ __launch_bounds__(TPB) void milecut_row_kernel(
    const float* __restrict__ trunc,
    const float* __restrict__ view1,
    const float* __restrict__ view2,
    const float* __restrict__ view3,
    const float* __restrict__ labels,
    float* __restrict__ partials)
{
    const int t    = threadIdx.x;
    const int lane = t & 63;
    const int wv   = t >> 6;
    const int row0 = blockIdx.x * RPB;

    __shared__ unsigned swtot[NW];        // packed wave scan totals (reused per row)
    __shared__ float    srow[RPB][NW][2]; // (esum, wtr) per row per wave
    __shared__ float    sbce[NW];

    // ---- prefetch row 0: 10 independent fully-coalesced nontemporal 16B loads ----
    size_t off = (size_t)row0 * L_DIM;
    v4f nya = ntload(labels + off + 4 * t);
    v4f nyb = ntload(labels + off + 4 * (t + 256));
    v4f nta = ntload(trunc  + off + 4 * t);
    v4f ntb = ntload(trunc  + off + 4 * (t + 256));
    v4f n1a = ntload(view1  + off + 4 * t);
    v4f n1b = ntload(view1  + off + 4 * (t + 256));
    v4f n2a = ntload(view2  + off + 4 * t);
    v4f n2b = ntload(view2  + off + 4 * (t + 256));
    v4f n3a = ntload(view3  + off + 4 * t);
    v4f n3b = ntload(view3  + off + 4 * (t + 256));

    float bce = 0.f;   // per-thread, across all RPB rows

    #pragma unroll
    for (int rr = 0; rr < RPB; ++rr) {
        // move current row into working regs
        v4f ya = nya, yb = nyb, ta = nta, tb = ntb;
        v4f u1a = n1a, u1b = n1b, u2a = n2a, u2b = n2b, u3a = n3a, u3b = n3b;
        // issue next row's loads NOW (consumed only next iteration)
        if (rr + 1 < RPB) {
            size_t o2 = (size_t)(row0 + rr + 1) * L_DIM;
            nya = ntload(labels + o2 + 4 * t);
            nyb = ntload(labels + o2 + 4 * (t + 256));
            nta = ntload(trunc  + o2 + 4 * t);
            ntb = ntload(trunc  + o2 + 4 * (t + 256));
            n1a = ntload(view1  + o2 + 4 * t);
            n1b = ntload(view1  + o2 + 4 * (t + 256));
            n2a = ntload(view2  + o2 + 4 * t);
            n2b = ntload(view2  + o2 + 4 * (t + 256));
            n3a = ntload(view3  + o2 + 4 * t);
            n3b = ntload(view3  + o2 + 4 * (t + 256));
        }

        // ---- label bitmasks; thread owns elements [4t..4t+3] and [1024+4t..] ----
        unsigned m1 = (ya.x > 0.5f ? 1u : 0u) | (ya.y > 0.5f ? 2u : 0u)
                    | (ya.z > 0.5f ? 4u : 0u) | (ya.w > 0.5f ? 8u : 0u);
        unsigned m2 = (yb.x > 0.5f ? 1u : 0u) | (yb.y > 0.5f ? 2u : 0u)
                    | (yb.z > 0.5f ? 4u : 0u) | (yb.w > 0.5f ? 8u : 0u);
        // packed per-thread sums: lo16 = group1 count, hi16 = group2 count
        unsigned pv = (unsigned)__popc(m1) | ((unsigned)__popc(m2) << 16);

        // ---- single packed inclusive wave scan (6 shfls) ----
        unsigned incl = pv;
        #pragma unroll
        for (int o = 1; o < 64; o <<= 1) {
            unsigned n = (unsigned)__shfl_up((int)incl, o, 64);
            if (lane >= o) incl += n;
        }
        if (lane == 63) swtot[wv] = incl;
        __syncthreads();
        unsigned pref = 0, tot = 0;
        #pragma unroll
        for (int w = 0; w < NW; ++w) {
            unsigned x = swtot[w];
            if (w < wv) pref += x;
            tot += x;
        }
        __syncthreads();   // protects swtot reuse next row

        unsigned eo    = incl - pv;                       // exclusive, packed (no borrow)
        unsigned excl1 = (pref & 0xffffu) + (eo & 0xffffu);
        unsigned tot1  = tot & 0xffffu;
        unsigned excl2 = tot1 + (pref >> 16) + (eo >> 16);
        float ftotal   = (float)(tot1 + (tot >> 16));     // row label total

        // ---- fused elementwise ----
        // r = 2*cum/(k+total); e = exp(r/tau); softmax norm deferred.
        // trunc: wtr_raw = sum log(t)*e; add LOG_TAU_INV*esum at row end.
        // bce: one log of the 6-factor product per j (see header comment).
        float esum = 0.f, wtr = 0.f;
        float tva[4] = {ta.x, ta.y, ta.z, ta.w};
        float tvb[4] = {tb.x, tb.y, tb.z, tb.w};
        float w1a[4] = {u1a.x, u1a.y, u1a.z, u1a.w};
        float w1b[4] = {u1b.x, u1b.y, u1b.z, u1b.w};
        float w2a[4] = {u2a.x, u2a.y, u2a.z, u2a.w};
        float w2b[4] = {u2b.x, u2b.y, u2b.z, u2b.w};
        float w3a[4] = {u3a.x, u3a.y, u3a.z, u3a.w};
        float w3b[4] = {u3b.x, u3b.y, u3b.z, u3b.w};
        const float two_tauinv = 2.0f * TAU_INV;
        #pragma unroll
        for (int j = 0; j < 4; ++j) {
            // softmax numerators (group1: elem 4t+j; group2: elem 1024+4t+j)
            unsigned c1 = excl1 + (unsigned)__popc(m1 & ((2u << j) - 1u));
            unsigned c2 = excl2 + (unsigned)__popc(m2 & ((2u << j) - 1u));
            float d1 = (float)(4 * t + j + 1) + ftotal;
            float d2 = (float)(1024 + 4 * t + j + 1) + ftotal;
            float e1 = __expf(two_tauinv * (float)c1 * __builtin_amdgcn_rcpf(d1));
            float e2 = __expf(two_tauinv * (float)c2 * __builtin_amdgcn_rcpf(d2));
            esum += e1 + e2;
            wtr  += __logf(tva[j]) * e1 + __logf(tvb[j]) * e2;
            // bce: product of the 6 selected probabilities, one log
            bool p1 = (m1 >> j) & 1u;
            bool p2 = (m2 >> j) & 1u;
            float q1 = p1 ? w1a[j] : 1.f - w1a[j];
            float q2 = p1 ? w2a[j] : 1.f - w2a[j];
            float q3 = p1 ? w3a[j] : 1.f - w3a[j];
            float q4 = p2 ? w1b[j] : 1.f - w1b[j];
            float q5 = p2 ? w2b[j] : 1.f - w2b[j];
            float q6 = p2 ? w3b[j] : 1.f - w3b[j];
            bce += __logf(((q1 * q2) * (q3 * q4)) * (q5 * q6));
        }
        wtr += LOG_TAU_INV * esum;   // fold the /tau back in, once per row-chunk

        // ---- wave-local reduce (no barrier); stash in per-(row,wave) slot ----
        #pragma unroll
        for (int o = 32; o > 0; o >>= 1) {
            esum += __shfl_down(esum, o, 64);
            wtr  += __shfl_down(wtr,  o, 64);
        }
        if (lane == 0) { srow[rr][wv][0] = esum; srow[rr][wv][1] = wtr; }
    }

    // ---- epilogue: bce wave reduce + single combine ----
    #pragma unroll
    for (int o = 32; o > 0; o >>= 1) bce += __shfl_down(bce, o, 64);
    if (lane == 0) sbce[wv] = bce;
    __syncthreads();
    if (t == 0) {
        float btot = sbce[0] + sbce[1] + sbce[2] + sbce[3];
        float atr = 0.f;
        #pragma unroll
        for (int rr = 0; rr < RPB; ++rr) {
            float es = srow[rr][0][0] + srow[rr][1][0] + srow[rr][2][0] + srow[rr][3][0];
            float wt = srow[rr][0][1] + srow[rr][1][1] + srow[rr][2][1] + srow[rr][3][1];
            atr += wt / es;             // this row's sum_j log(t/tau)*q_j
        }
        partials[blockIdx.x]        = atr;
        partials[NBLK + blockIdx.x] = btot;
    }
}

__global__ __launch_bounds__(TPB) void milecut_final_kernel(
    const float* __restrict__ partials, float* __restrict__ out)
{
    const int t = threadIdx.x;
    const float4* p4 = (const float4*)partials;   // 512 float4 total
    float4 a = p4[t];          // trunc region: f4 0..255
    float4 b = p4[256 + t];    // bce region:   f4 256..511
    float st = (a.x + a.y) + (a.z + a.w);
    float sb = (b.x + b.y) + (b.z + b.w);
    #pragma unroll
    for (int o = 32; o > 0; o >>= 1) {
        st += __shfl_down(st, o, 64);
        sb += __shfl_down(sb, o, 64);
    }
    __shared__ float s1[NW], s2[NW];
    const int lane = t & 63, wv = t >> 6;
    if (lane == 0) { s1[wv] = st; s2[wv] = sb; }
    __syncthreads();
    if (t == 0) {
        double St = 0.0, Sb = 0.0;
        #pragma unroll
        for (int w = 0; w < NW; ++w) { St += (double)s1[w]; Sb += (double)s2[w]; }
        double trunc_loss = -St / (double)B_DIM;                         // -sum(log*q)/B
        double vsum = -Sb / ((double)B_DIM * (double)L_DIM * (double)B_DIM);
        out[0] = (float)(0.5 * trunc_loss + 0.5 * vsum);
    }
}

extern "C" void kernel_launch(void* const* d_in, const int* in_sizes, int n_in,
                              void* d_out, int out_size, void* d_ws, size_t ws_size,
                              hipStream_t stream) {
    const float* trunc  = (const float*)d_in[0];
    const float* v1     = (const float*)d_in[1];
    const float* v2     = (const float*)d_in[2];
    const float* v3     = (const float*)d_in[3];
    const float* labels = (const float*)d_in[4];

    float* partials = (float*)d_ws;  // 2*NBLK*4 = 8 KB used

    milecut_row_kernel<<<NBLK, TPB, 0, stream>>>(trunc, v1, v2, v3, labels, partials);
    milecut_final_kernel<<<1, TPB, 0, stream>>>(partials, (float*)d_out);
}